// Round 19
// baseline (128.315 us; speedup 1.0000x reference)
//
#include <hip/hip_runtime.h>

// UnionRGCNLayer, Wn-pushed-through + 16-node micro-bucket k_fused (persistent grid,
// occupancy-capped):
//   out = relu( nf*( hsum@(Whp_h@Wn) + psum@(Whp_p@Wn) + Sum_e (emb[type]+b)@Wn ) + h@Lw )
//   hsum = Sum_e h[src], psum = Sum_e pos[src]; deg==0 rows: out = relu(h@Ew) (rare patch)
//   k_zero: zero gcnt (kernel, not graph memset node)
//   k_comb (grid = 256 exactly): [0,nBB) bin 8k edges -> 16-dst buckets;
//     [nBB,+nPB) pack h16/WpW/LwFrag + zero-rows; [+nEB) MFMA EWn16; [+2) MFMA WhpWnFrag
//   k_fused: grid = 2048, __launch_bounds__(256,8) caps VGPR at 64 (R18's persistent loop
//     pushed VGPR to 88 -> occupancy halved at the 64-reg step, m69). Each block loops
//     bkt += 2048 -- removes the 2500-vs-2048 ragged second round.
// MFMA packing convention (consistent A/B; k-permutation cancels):
//   A: lane l elem j -> A[l&15][(l>>4)*8+j];  B: lane l elem j -> B[(l>>4)*8+j][l&15]
//   C/D (m89-verified): lane l reg r -> D[(l>>4)*4+r][l&15]

#define BS 768         // bucket capacity (mean 256, ~32 sigma headroom)
#define CAP2 48        // per-dst list cap (Poisson(16): P(>48) ~ 1e-12); multiple of 8
#define CH 8192        // edges per bin block
#define FGRID 2048     // k_fused persistent grid (8 blocks/CU x 256 CU)

typedef __bf16 bf16x8 __attribute__((ext_vector_type(8)));
typedef float f32x4 __attribute__((ext_vector_type(4)));
typedef unsigned short u16x4 __attribute__((ext_vector_type(4)));

__device__ inline unsigned short f2bf(float f) {
    unsigned u = __float_as_uint(f);
    u += 0x7fffu + ((u >> 16) & 1u);
    return (unsigned short)(u >> 16);
}
__device__ inline float bflo(unsigned u) { return __uint_as_float(u << 16); }
__device__ inline float bfhi(unsigned u) { return __uint_as_float(u & 0xffff0000u); }

// ---------------- k_zero ----------------
__global__ __launch_bounds__(512) void k_zero(int* __restrict__ gcnt, int nbkt) {
    int i = blockIdx.x * blockDim.x + threadIdx.x;
    if (i < nbkt) gcnt[i] = 0;
}

// ---------------- k_comb: bin + pack + MFMA precompute ----------------
__global__ __launch_bounds__(512) void k_comb(const float* __restrict__ h,
                                              const float* __restrict__ Whp,
                                              const float* __restrict__ bhp,
                                              const float* __restrict__ Wn,
                                              const float* __restrict__ Lw,
                                              const float* __restrict__ emb, int R,
                                              const int* __restrict__ esrc,
                                              const int* __restrict__ edst,
                                              const int* __restrict__ etyp, int E,
                                              int* __restrict__ gcnt,
                                              unsigned* __restrict__ gbuf,
                                              unsigned short* __restrict__ h16,
                                              unsigned short* __restrict__ EWn16,
                                              unsigned short* __restrict__ WhpWnFrag,
                                              float* __restrict__ WpW,
                                              unsigned short* __restrict__ LwFrag,
                                              int nBB, int nPB, int nEB, int nbkt, int N) {
    __shared__ int binLds[5120];                 // bin path: lcnt + lbase (2 x nbkt)
    __shared__ unsigned short Xs[64][136];       // GEMM A tile (bf16)
    __shared__ unsigned short WnT[128][40];      // GEMM B chunk, transposed (bf16)
    const int tid = threadIdx.x;

    if (blockIdx.x < nBB) {
        int* lcnt = binLds;
        int* lbase = binLds + 2560;
        const int e0 = blockIdx.x * CH;
        const int eN = min(E - e0, CH);
        for (int i = tid; i < nbkt; i += 512) lcnt[i] = 0;
        __syncthreads();
        for (int base = tid * 4; base < eN; base += 2048) {
            if (base + 3 < eN) {
                int4 d4 = *reinterpret_cast<const int4*>(&edst[e0 + base]);
                atomicAdd(&lcnt[d4.x >> 4], 1);
                atomicAdd(&lcnt[d4.y >> 4], 1);
                atomicAdd(&lcnt[d4.z >> 4], 1);
                atomicAdd(&lcnt[d4.w >> 4], 1);
            } else {
                for (int k = 0; k < 4 && base + k < eN; k++)
                    atomicAdd(&lcnt[edst[e0 + base + k] >> 4], 1);
            }
        }
        __syncthreads();
        for (int i = tid; i < nbkt; i += 512) {
            int c = lcnt[i];
            lbase[i] = c ? atomicAdd(&gcnt[i], c) : 0;
        }
        __syncthreads();
        for (int i = tid; i < nbkt; i += 512) lcnt[i] = 0;
        __syncthreads();
        for (int base = tid * 4; base < eN; base += 2048) {
            if (base + 3 < eN) {
                int4 d4 = *reinterpret_cast<const int4*>(&edst[e0 + base]);
                int4 s4 = *reinterpret_cast<const int4*>(&esrc[e0 + base]);
                int4 t4 = *reinterpret_cast<const int4*>(&etyp[e0 + base]);
                int dd[4] = {d4.x, d4.y, d4.z, d4.w};
                int ss[4] = {s4.x, s4.y, s4.z, s4.w};
                int tt[4] = {t4.x, t4.y, t4.z, t4.w};
#pragma unroll
                for (int k = 0; k < 4; k++) {
                    int b = dd[k] >> 4;
                    unsigned val = (unsigned)(dd[k] & 15) | ((unsigned)ss[k] << 4)
                                 | ((unsigned)tt[k] << 20);
                    int off = atomicAdd(&lcnt[b], 1);
                    gbuf[(size_t)b * BS + min(lbase[b] + off, BS - 1)] = val;
                }
            } else {
                for (int k = 0; k < 4 && base + k < eN; k++) {
                    int d = edst[e0 + base + k];
                    int b = d >> 4;
                    unsigned val = (unsigned)(d & 15) | ((unsigned)esrc[e0 + base + k] << 4)
                                 | ((unsigned)etyp[e0 + base + k] << 20);
                    int off = atomicAdd(&lcnt[b], 1);
                    gbuf[(size_t)b * BS + min(lbase[b] + off, BS - 1)] = val;
                }
            }
        }
        return;
    }

    if (blockIdx.x < nBB + nPB) {
        // ---- pack blocks: h16, zero rows, WpW (tiny), LwFrag ----
        const int gid0 = (blockIdx.x - nBB) * 512 + tid;
        const int gs = nPB * 512;
        for (int i = gid0; i < N * 32; i += gs) {      // h16 = bf16(h)
            int row = i >> 5, q = i & 31;
            float4 a = *reinterpret_cast<const float4*>(h + (size_t)row * 128 + q * 4);
            u16x4 v;
            v[0] = f2bf(a.x); v[1] = f2bf(a.y); v[2] = f2bf(a.z); v[3] = f2bf(a.w);
            *reinterpret_cast<u16x4*>(&h16[(size_t)row * 128 + q * 4]) = v;
        }
        if (gid0 < 128) {                              // zero rows for dummy-pad gather
            h16[(size_t)N * 128 + gid0] = 0;
            EWn16[(size_t)R * 128 + gid0] = 0;
        }
        for (int i = gid0; i < 384; i += gs) {         // WpW = Whp[128:131]@Wn (fp32)
            int r = i >> 7, cc = i & 127;
            float s = 0.f;
#pragma unroll 4
            for (int q = 0; q < 128; q++) s += Whp[(128 + r) * 128 + q] * Wn[q * 128 + cc];
            WpW[i] = s;
        }
        for (int i = gid0; i < 16384; i += gs) {       // LwFrag (pure permute)
            int j = i & 7, l = (i >> 3) & 63, nt = (i >> 9) & 7, c = i >> 12;
            int k = c * 32 + ((l >> 4) << 3) + j;
            int n = nt * 16 + (l & 15);
            LwFrag[i] = f2bf(Lw[k * 128 + n]);
        }
        return;
    }

    // ---- MFMA GEMM blocks: EWn16 (nEB) then WhpWnFrag (2) ----
    {
        const int gb = blockIdx.x - nBB - nPB;
        const bool isE = gb < nEB;
        const int rbase = isE ? gb * 64 : (gb - nEB) * 64;
        const int w = tid >> 6, l = tid & 63;
#pragma unroll
        for (int it = 0; it < 4; it++) {
            int qid = tid + it * 512;
            int rr = qid >> 5, cq = qid & 31;
            int row = rbase + rr;
            u16x4 v = {0, 0, 0, 0};
            if (isE) {
                if (row < R) {
                    float4 a = *reinterpret_cast<const float4*>(emb + (size_t)row * 128 + cq * 4);
                    float4 b4 = *reinterpret_cast<const float4*>(bhp + cq * 4);
                    v[0] = f2bf(a.x + b4.x); v[1] = f2bf(a.y + b4.y);
                    v[2] = f2bf(a.z + b4.z); v[3] = f2bf(a.w + b4.w);
                }
            } else {
                float4 a = *reinterpret_cast<const float4*>(Whp + (size_t)row * 128 + cq * 4);
                v[0] = f2bf(a.x); v[1] = f2bf(a.y); v[2] = f2bf(a.z); v[3] = f2bf(a.w);
            }
            *reinterpret_cast<u16x4*>(&Xs[rr][cq * 4]) = v;
        }
        f32x4 acc[4];
#pragma unroll
        for (int i = 0; i < 4; i++) acc[i] = (f32x4){0.f, 0.f, 0.f, 0.f};
        const int rt = w >> 1, chh = w & 1;
#pragma unroll 1
        for (int c = 0; c < 4; c++) {
            __syncthreads();
#pragma unroll
            for (int it = 0; it < 2; it++) {
                int qid = tid + it * 512;
                int kk = qid >> 5, cq = qid & 31;
                float4 a = *reinterpret_cast<const float4*>(Wn + (size_t)(c * 32 + kk) * 128 + cq * 4);
                WnT[cq * 4 + 0][kk] = f2bf(a.x);
                WnT[cq * 4 + 1][kk] = f2bf(a.y);
                WnT[cq * 4 + 2][kk] = f2bf(a.z);
                WnT[cq * 4 + 3][kk] = f2bf(a.w);
            }
            __syncthreads();
            bf16x8 a = *reinterpret_cast<const bf16x8*>(&Xs[rt * 16 + (l & 15)][c * 32 + (l >> 4) * 8]);
#pragma unroll
            for (int n2 = 0; n2 < 4; n2++) {
                int n = (chh * 4 + n2) * 16 + (l & 15);
                bf16x8 b = *reinterpret_cast<const bf16x8*>(&WnT[n][(l >> 4) * 8]);
                acc[n2] = __builtin_amdgcn_mfma_f32_16x16x32_bf16(a, b, acc[n2], 0, 0, 0);
            }
        }
        const int lrow0 = rt * 16 + ((l >> 4) << 2);
#pragma unroll
        for (int n2 = 0; n2 < 4; n2++) {
            int col = (chh * 4 + n2) * 16 + (l & 15);
#pragma unroll
            for (int r = 0; r < 4; r++) {
                int row = rbase + lrow0 + r;
                if (isE) {
                    if (row < R) EWn16[(size_t)row * 128 + col] = f2bf(acc[n2][r]);
                } else {
                    int c_out = row >> 5, rem = row & 31;
                    int i = c_out * 4096 + (col >> 4) * 512
                          + ((rem >> 3) * 16 + (col & 15)) * 8 + (rem & 7);
                    WhpWnFrag[i] = f2bf(acc[n2][r]);
                }
            }
        }
    }
}

// ---------------- persistent fused kernel (256 thr, grid 2048, >=8 waves/EU) ----------------
__global__ __launch_bounds__(256, 8) void k_fused(const float* __restrict__ h,
                                                  const float* __restrict__ pos,
                                                  const float* __restrict__ nrm,
                                                  const unsigned short* __restrict__ h16,
                                                  const unsigned short* __restrict__ EWn16,
                                                  const int* __restrict__ gcnt,
                                                  const unsigned* __restrict__ gbuf,
                                                  const unsigned short* __restrict__ WhpWnFrag,
                                                  const unsigned short* __restrict__ LwFrag,
                                                  const float* __restrict__ WpW,
                                                  const float* __restrict__ Ew,
                                                  const float* __restrict__ Lwp,
                                                  const float* __restrict__ Ewp,
                                                  float* __restrict__ out,
                                                  int nbkt, int N, int R) {
    __shared__ unsigned eplists[16][CAP2];       // 3 KB
    __shared__ int lcnt2[16];
    __shared__ float psumS[16][4];
    __shared__ unsigned short hpsumS[16][136];   // 4.25 KB
    __shared__ unsigned short esumS[16][136];    // 4.25 KB
    __shared__ unsigned short hsh[16][136];      // 4.25 KB
    __shared__ float WpWS[3][128];
    __shared__ float nrmS[16];
    __shared__ int zrowsS[16];
    __shared__ int nzS;
    const int tid = threadIdx.x;
    const int w = tid >> 6, lane = tid & 63;
    const int half = lane >> 5;
    const int g = (lane >> 4) & 1, l16 = lane & 15;
    const unsigned dummy = (unsigned)N | ((unsigned)R << 16);
    const uint4* h4 = reinterpret_cast<const uint4*>(h16);
    const uint4* e4 = reinterpret_cast<const uint4*>(EWn16);

    if (tid >= 64 && tid < 192) {   // once: WpW staging
        int i = tid - 64;
        WpWS[0][i] = WpW[i]; WpWS[1][i] = WpW[128 + i]; WpWS[2][i] = WpW[256 + i];
    }

#pragma unroll 1
    for (int bkt = blockIdx.x; bkt < nbkt; bkt += FGRID) {
        const int rbase = bkt * 16;
        __syncthreads();   // prior iteration's reads complete before re-init

        // init: dummy-fill eplists (tail entries -> zero rows), per-bucket scalars
        {
            unsigned* ep = &eplists[0][0];
            for (int i = tid; i < 16 * CAP2; i += 256) ep[i] = dummy;
        }
        if (tid == 192) nzS = 0;
        if (tid < 16) {
            int row = rbase + tid;
            nrmS[tid] = (row < N) ? nrm[row] : 0.f;
            lcnt2[tid] = 0;
        }
        __syncthreads();

        // phase 0: re-bin bucket into per-dst LDS lists
        const int cntB = min(gcnt[bkt], BS);
        for (int i = tid; i < cntB; i += 256) {
            unsigned v = gbuf[(size_t)bkt * BS + i];
            int d = v & 15;
            int off = atomicAdd(&lcnt2[d], 1);
            if (off < CAP2) eplists[d][off] = v >> 4;   // src | type<<16
        }
        __syncthreads();

        if (tid < 16) {
            int row = rbase + tid;
            if (row < N && lcnt2[tid] == 0) {
                int o = atomicAdd(&nzS, 1);
                zrowsS[o] = tid;
            }
        }
        // psum: 48 dedicated threads, exact fp32, no atomics (overlaps others' phase 1)
        if (tid < 64) {
            int d = tid >> 2, j = tid & 3;
            if (j < 3) {
                float s = 0.f;
                int m = min(lcnt2[d], CAP2);
                int i = 0;
                for (; i + 4 <= m; i += 4) {
                    unsigned s0 = eplists[d][i] & 0xffffu;
                    unsigned s1 = eplists[d][i + 1] & 0xffffu;
                    unsigned s2 = eplists[d][i + 2] & 0xffffu;
                    unsigned s3 = eplists[d][i + 3] & 0xffffu;
                    float a = pos[(size_t)s0 * 3 + j];
                    float b = pos[(size_t)s1 * 3 + j];
                    float c = pos[(size_t)s2 * 3 + j];
                    float e = pos[(size_t)s3 * 3 + j];
                    s += (a + b) + (c + e);
                }
                for (; i < m; i++) s += pos[(size_t)(eplists[d][i] & 0xffffu) * 3 + j];
                psumS[d][j] = s;
            }
        }

        // phase 1: 2 passes x 8 streams; g0 sums h16 rows, g1 sums EWn16 rows.
        // No masking: tail entries are dummies reading zero rows.
#pragma unroll 1
        for (int p = 0; p < 2; p++) {
            const int base2 = p * 8 + w * 2;
            const int vl = base2 + half;
            const int mm = (max(min(lcnt2[base2], CAP2), min(lcnt2[base2 + 1], CAP2)) + 7) & ~7;
            float a[8];
#pragma unroll
            for (int r = 0; r < 8; r++) a[r] = 0.f;
            const unsigned* epr = &eplists[vl][0];
            const uint4* basep = g ? e4 : h4;
#pragma unroll 1
            for (int j = 0; j < mm; j += 8) {
                uint4 rv[8];
#pragma unroll
                for (int u = 0; u < 8; u++) {
                    unsigned pk = epr[j + u];
                    unsigned ridx = g ? (pk >> 16) : (pk & 0xffffu);
                    rv[u] = basep[(size_t)ridx * 16u + l16];
                }
#pragma unroll
                for (int u = 0; u < 8; u++) {
                    a[0] += bflo(rv[u].x); a[1] += bfhi(rv[u].x);
                    a[2] += bflo(rv[u].y); a[3] += bfhi(rv[u].y);
                    a[4] += bflo(rv[u].z); a[5] += bfhi(rv[u].z);
                    a[6] += bflo(rv[u].w); a[7] += bfhi(rv[u].w);
                }
            }
            float nf = nrmS[vl];
            unsigned pk4[4];
#pragma unroll
            for (int q = 0; q < 4; q++) {
                pk4[q] = (unsigned)f2bf(nf * a[2 * q]) | ((unsigned)f2bf(nf * a[2 * q + 1]) << 16);
            }
            unsigned short* dst = g ? &esumS[vl][0] : &hpsumS[vl][0];
            *reinterpret_cast<uint4*>(&dst[l16 * 8]) = make_uint4(pk4[0], pk4[1], pk4[2], pk4[3]);
        }

        // stage h tile from h16 (one uint4 per thread)
        {
            int row = rbase + (tid >> 4);
            uint4 v = make_uint4(0, 0, 0, 0);
            if (row < N) v = h4[(size_t)row * 16 + (tid & 15)];
            *reinterpret_cast<uint4*>(&hsh[tid >> 4][(tid & 15) * 8]) = v;
        }
        __syncthreads();

        // phase 2: acc = (nf*hsum)@WhpWn + h@Lw ; 4 waves x 2 col-tiles, M=16, 8 chunks
        f32x4 acc[2];
        acc[0] = (f32x4){0.f, 0.f, 0.f, 0.f};
        acc[1] = (f32x4){0.f, 0.f, 0.f, 0.f};
        const int arow = lane & 15;
#pragma unroll
        for (int c = 0; c < 8; c++) {
            uint4 raw;
            const bf16x8* Bp;
            if (c < 4) {
                raw = *reinterpret_cast<const uint4*>(&hpsumS[arow][c * 32 + (lane >> 4) * 8]);
                Bp = reinterpret_cast<const bf16x8*>(WhpWnFrag) + (size_t)c * 512;
            } else {
                raw = *reinterpret_cast<const uint4*>(&hsh[arow][(c & 3) * 32 + (lane >> 4) * 8]);
                Bp = reinterpret_cast<const bf16x8*>(LwFrag) + (size_t)(c & 3) * 512;
            }
            bf16x8 a = *reinterpret_cast<bf16x8*>(&raw);
#pragma unroll
            for (int n2 = 0; n2 < 2; n2++) {
                bf16x8 b = Bp[(w * 2 + n2) * 64 + lane];
                acc[n2] = __builtin_amdgcn_mfma_f32_16x16x32_bf16(a, b, acc[n2], 0, 0, 0);
            }
        }
        const int lrow0 = (lane >> 4) << 2;
#pragma unroll
        for (int n2 = 0; n2 < 2; n2++) {
            int col = (w * 2 + n2) * 16 + (lane & 15);
            float wp0 = WpWS[0][col], wp1 = WpWS[1][col], wp2 = WpWS[2][col];
#pragma unroll
            for (int r = 0; r < 4; r++) {
                int lr = lrow0 + r;
                int grow = rbase + lr;
                if (grow < N && lcnt2[lr] > 0) {
                    float nfr = nrmS[lr];
                    float es = bflo((unsigned)esumS[lr][col]);
                    float pterm = psumS[lr][0] * wp0 + psumS[lr][1] * wp1 + psumS[lr][2] * wp2;
                    float v = acc[n2][r] + es + nfr * pterm;
                    out[(size_t)grow * 128 + col] = fmaxf(v, 0.f);
                }
            }
        }
        // rare deg==0 patch: out = relu(h @ Ew), exact fp32 (block-uniform, ~never runs)
        for (int zi = 0; zi < nzS; zi++) {
            int r = zrowsS[zi];
            int row = rbase + r;
            if (tid < 128) {
                float accp = 0.f;
                for (int k = 0; k < 128; k++)
                    accp += h[(size_t)row * 128 + k] * Ew[k * 128 + tid];
                out[(size_t)row * 128 + tid] = fmaxf(accp, 0.f);
            }
        }
        // pos path
        if (tid < 16) {
            int row = rbase + tid;
            if (row < N) {
                float p0 = pos[(size_t)row * 3 + 0];
                float p1 = pos[(size_t)row * 3 + 1];
                float p2 = pos[(size_t)row * 3 + 2];
                const float* M = (lcnt2[tid] > 0) ? Lwp : Ewp;
                float o0 = p0 + (p0 * M[0] + p1 * M[3] + p2 * M[6]);
                float o1 = p1 + (p0 * M[1] + p1 * M[4] + p2 * M[7]);
                float o2 = p2 + (p0 * M[2] + p1 * M[5] + p2 * M[8]);
                size_t base = (size_t)N * 128 + (size_t)row * 3;
                out[base + 0] = fmaxf(o0, 0.f);
                out[base + 1] = fmaxf(o1, 0.f);
                out[base + 2] = fmaxf(o2, 0.f);
            }
        }
    }
}

extern "C" void kernel_launch(void* const* d_in, const int* in_sizes, int n_in,
                              void* d_out, int out_size, void* d_ws, size_t ws_size,
                              hipStream_t stream) {
    const float* h   = (const float*)d_in[0];
    const float* pos = (const float*)d_in[1];
    const float* nrm = (const float*)d_in[2];
    const float* emb = (const float*)d_in[3];
    const float* Whp = (const float*)d_in[4];
    const float* bhp = (const float*)d_in[5];
    const float* Wn  = (const float*)d_in[6];
    const float* Lw  = (const float*)d_in[7];
    const float* Ew  = (const float*)d_in[8];
    const float* Lwp = (const float*)d_in[9];
    const float* Ewp = (const float*)d_in[10];
    const int* esrc  = (const int*)d_in[11];
    const int* edst  = (const int*)d_in[12];
    const int* etyp  = (const int*)d_in[13];

    const int N = in_sizes[2];
    const int E = in_sizes[11];
    const int R = in_sizes[3] / 128;

    float* out = (float*)d_out;

    char* wsb = (char*)d_ws;
    size_t off = 0;
    auto nalloc = [&](size_t bytes) { char* p = wsb + off; off += (bytes + 255) & ~(size_t)255; return p; };
    const int nbkt = (N + 15) / 16;
    const int nEB = (R + 63) / 64;
    unsigned short* h16       = (unsigned short*)nalloc((size_t)(N + 1) * 128 * 2);  // +1 zero row
    int*            gcnt      = (int*)nalloc((size_t)nbkt * 4);
    unsigned*       gbuf      = (unsigned*)nalloc((size_t)nbkt * BS * 4);
    unsigned short* EWn16     = (unsigned short*)nalloc((size_t)(nEB * 64 + 1) * 128 * 2);
    unsigned short* WhpWnFrag = (unsigned short*)nalloc(16384 * 2);
    unsigned short* LwFrag    = (unsigned short*)nalloc(16384 * 2);
    float*          WpW       = (float*)nalloc(384 * 4);

    k_zero<<<(nbkt + 511) / 512, 512, 0, stream>>>(gcnt, nbkt);

    const int nBB = (E + CH - 1) / CH;
    const int nGB = nEB + 2;
    int nPB = 256 - nBB - nGB;
    if (nPB < 16) nPB = 16;
    k_comb<<<nBB + nPB + nGB, 512, 0, stream>>>(h, Whp, bhp, Wn, Lw, emb, R,
                                                esrc, edst, etyp, E,
                                                gcnt, gbuf, h16, EWn16,
                                                WhpWnFrag, WpW, LwFrag,
                                                nBB, nPB, nEB, nbkt, N);
    const int fgrid = (nbkt < FGRID) ? nbkt : FGRID;
    k_fused<<<fgrid, 256, 0, stream>>>(h, pos, nrm, h16, EWn16, gcnt, gbuf,
                                       WhpWnFrag, LwFrag, WpW, Ew, Lwp, Ewp, out,
                                       nbkt, N, R);
}

// Round 20
// 64.045 us; speedup vs baseline: 2.0035x; 2.0035x over previous
//
#include <hip/hip_runtime.h>

// UnionRGCNLayer, Wn-pushed-through + 16-node micro-bucket k_fused (R17 revert — best known):
//   out = relu( nf*( hsum@(Whp_h@Wn) + psum@(Whp_p@Wn) + Sum_e (emb[type]+b)@Wn ) + h@Lw )
//   hsum = Sum_e h[src], psum = Sum_e pos[src]; deg==0 rows: out = relu(h@Ew) (rare patch)
//   k_zero: zero gcnt (kernel, not graph memset node)
//   k_comb (grid = 256 exactly): [0,nBB) bin 8k edges -> 16-dst buckets;
//     [nBB,+nPB) pack h16/WpW/LwFrag + zero-rows; [+nEB) MFMA EWn16; [+2) MFMA WhpWnFrag
//   k_fused per 16-row block (256 thr, ~18KB LDS, flat grid nbkt):
//     phase0: eplists pre-filled with dummy (src=N,type=R -> ZERO rows) then rebin;
//             psum via 48 dedicated threads (no atomics)
//     phase1: 2 passes x 8 streams; g0 sums h16 rows, g1 EWn16 rows; NO masking --
//             padded entries read the zero rows (pure load+unpack+add)
//     phase2: acc = (nf*hsum)@WhpWnFrag + h@LwFrag; out = relu(acc + esum + nf*psum@WpW)
//     pos:    out_pos = relu(pos + pos @ (deg>0 ? Lwp : Ewp))
//   NOTE: persistent-grid variants refuted — R18 (natural alloc): VGPR 88 -> occupancy
//   halved at 64-reg step (m69); R19 (forced 8 waves/EU): scratch spills, 225MB WRITE.
// MFMA packing convention (consistent A/B; k-permutation cancels):
//   A: lane l elem j -> A[l&15][(l>>4)*8+j];  B: lane l elem j -> B[(l>>4)*8+j][l&15]
//   C/D (m89-verified): lane l reg r -> D[(l>>4)*4+r][l&15]

#define BS 768         // bucket capacity (mean 256, ~32 sigma headroom)
#define CAP2 48        // per-dst list cap (Poisson(16): P(>48) ~ 1e-12); multiple of 8
#define CH 8192        // edges per bin block

typedef __bf16 bf16x8 __attribute__((ext_vector_type(8)));
typedef float f32x4 __attribute__((ext_vector_type(4)));
typedef unsigned short u16x4 __attribute__((ext_vector_type(4)));

__device__ inline unsigned short f2bf(float f) {
    unsigned u = __float_as_uint(f);
    u += 0x7fffu + ((u >> 16) & 1u);
    return (unsigned short)(u >> 16);
}
__device__ inline float bflo(unsigned u) { return __uint_as_float(u << 16); }
__device__ inline float bfhi(unsigned u) { return __uint_as_float(u & 0xffff0000u); }

// ---------------- k_zero ----------------
__global__ __launch_bounds__(512) void k_zero(int* __restrict__ gcnt, int nbkt) {
    int i = blockIdx.x * blockDim.x + threadIdx.x;
    if (i < nbkt) gcnt[i] = 0;
}

// ---------------- k_comb: bin + pack + MFMA precompute ----------------
__global__ __launch_bounds__(512) void k_comb(const float* __restrict__ h,
                                              const float* __restrict__ Whp,
                                              const float* __restrict__ bhp,
                                              const float* __restrict__ Wn,
                                              const float* __restrict__ Lw,
                                              const float* __restrict__ emb, int R,
                                              const int* __restrict__ esrc,
                                              const int* __restrict__ edst,
                                              const int* __restrict__ etyp, int E,
                                              int* __restrict__ gcnt,
                                              unsigned* __restrict__ gbuf,
                                              unsigned short* __restrict__ h16,
                                              unsigned short* __restrict__ EWn16,
                                              unsigned short* __restrict__ WhpWnFrag,
                                              float* __restrict__ WpW,
                                              unsigned short* __restrict__ LwFrag,
                                              int nBB, int nPB, int nEB, int nbkt, int N) {
    __shared__ int binLds[5120];                 // bin path: lcnt + lbase (2 x nbkt)
    __shared__ unsigned short Xs[64][136];       // GEMM A tile (bf16)
    __shared__ unsigned short WnT[128][40];      // GEMM B chunk, transposed (bf16)
    const int tid = threadIdx.x;

    if (blockIdx.x < nBB) {
        int* lcnt = binLds;
        int* lbase = binLds + 2560;
        const int e0 = blockIdx.x * CH;
        const int eN = min(E - e0, CH);
        for (int i = tid; i < nbkt; i += 512) lcnt[i] = 0;
        __syncthreads();
        for (int base = tid * 4; base < eN; base += 2048) {
            if (base + 3 < eN) {
                int4 d4 = *reinterpret_cast<const int4*>(&edst[e0 + base]);
                atomicAdd(&lcnt[d4.x >> 4], 1);
                atomicAdd(&lcnt[d4.y >> 4], 1);
                atomicAdd(&lcnt[d4.z >> 4], 1);
                atomicAdd(&lcnt[d4.w >> 4], 1);
            } else {
                for (int k = 0; k < 4 && base + k < eN; k++)
                    atomicAdd(&lcnt[edst[e0 + base + k] >> 4], 1);
            }
        }
        __syncthreads();
        for (int i = tid; i < nbkt; i += 512) {
            int c = lcnt[i];
            lbase[i] = c ? atomicAdd(&gcnt[i], c) : 0;
        }
        __syncthreads();
        for (int i = tid; i < nbkt; i += 512) lcnt[i] = 0;
        __syncthreads();
        for (int base = tid * 4; base < eN; base += 2048) {
            if (base + 3 < eN) {
                int4 d4 = *reinterpret_cast<const int4*>(&edst[e0 + base]);
                int4 s4 = *reinterpret_cast<const int4*>(&esrc[e0 + base]);
                int4 t4 = *reinterpret_cast<const int4*>(&etyp[e0 + base]);
                int dd[4] = {d4.x, d4.y, d4.z, d4.w};
                int ss[4] = {s4.x, s4.y, s4.z, s4.w};
                int tt[4] = {t4.x, t4.y, t4.z, t4.w};
#pragma unroll
                for (int k = 0; k < 4; k++) {
                    int b = dd[k] >> 4;
                    unsigned val = (unsigned)(dd[k] & 15) | ((unsigned)ss[k] << 4)
                                 | ((unsigned)tt[k] << 20);
                    int off = atomicAdd(&lcnt[b], 1);
                    gbuf[(size_t)b * BS + min(lbase[b] + off, BS - 1)] = val;
                }
            } else {
                for (int k = 0; k < 4 && base + k < eN; k++) {
                    int d = edst[e0 + base + k];
                    int b = d >> 4;
                    unsigned val = (unsigned)(d & 15) | ((unsigned)esrc[e0 + base + k] << 4)
                                 | ((unsigned)etyp[e0 + base + k] << 20);
                    int off = atomicAdd(&lcnt[b], 1);
                    gbuf[(size_t)b * BS + min(lbase[b] + off, BS - 1)] = val;
                }
            }
        }
        return;
    }

    if (blockIdx.x < nBB + nPB) {
        // ---- pack blocks: h16, zero rows, WpW (tiny), LwFrag ----
        const int gid0 = (blockIdx.x - nBB) * 512 + tid;
        const int gs = nPB * 512;
        for (int i = gid0; i < N * 32; i += gs) {      // h16 = bf16(h)
            int row = i >> 5, q = i & 31;
            float4 a = *reinterpret_cast<const float4*>(h + (size_t)row * 128 + q * 4);
            u16x4 v;
            v[0] = f2bf(a.x); v[1] = f2bf(a.y); v[2] = f2bf(a.z); v[3] = f2bf(a.w);
            *reinterpret_cast<u16x4*>(&h16[(size_t)row * 128 + q * 4]) = v;
        }
        if (gid0 < 128) {                              // zero rows for dummy-pad gather
            h16[(size_t)N * 128 + gid0] = 0;
            EWn16[(size_t)R * 128 + gid0] = 0;
        }
        for (int i = gid0; i < 384; i += gs) {         // WpW = Whp[128:131]@Wn (fp32)
            int r = i >> 7, cc = i & 127;
            float s = 0.f;
#pragma unroll 4
            for (int q = 0; q < 128; q++) s += Whp[(128 + r) * 128 + q] * Wn[q * 128 + cc];
            WpW[i] = s;
        }
        for (int i = gid0; i < 16384; i += gs) {       // LwFrag (pure permute)
            int j = i & 7, l = (i >> 3) & 63, nt = (i >> 9) & 7, c = i >> 12;
            int k = c * 32 + ((l >> 4) << 3) + j;
            int n = nt * 16 + (l & 15);
            LwFrag[i] = f2bf(Lw[k * 128 + n]);
        }
        return;
    }

    // ---- MFMA GEMM blocks: EWn16 (nEB) then WhpWnFrag (2) ----
    {
        const int gb = blockIdx.x - nBB - nPB;
        const bool isE = gb < nEB;
        const int rbase = isE ? gb * 64 : (gb - nEB) * 64;
        const int w = tid >> 6, l = tid & 63;
#pragma unroll
        for (int it = 0; it < 4; it++) {
            int qid = tid + it * 512;
            int rr = qid >> 5, cq = qid & 31;
            int row = rbase + rr;
            u16x4 v = {0, 0, 0, 0};
            if (isE) {
                if (row < R) {
                    float4 a = *reinterpret_cast<const float4*>(emb + (size_t)row * 128 + cq * 4);
                    float4 b4 = *reinterpret_cast<const float4*>(bhp + cq * 4);
                    v[0] = f2bf(a.x + b4.x); v[1] = f2bf(a.y + b4.y);
                    v[2] = f2bf(a.z + b4.z); v[3] = f2bf(a.w + b4.w);
                }
            } else {
                float4 a = *reinterpret_cast<const float4*>(Whp + (size_t)row * 128 + cq * 4);
                v[0] = f2bf(a.x); v[1] = f2bf(a.y); v[2] = f2bf(a.z); v[3] = f2bf(a.w);
            }
            *reinterpret_cast<u16x4*>(&Xs[rr][cq * 4]) = v;
        }
        f32x4 acc[4];
#pragma unroll
        for (int i = 0; i < 4; i++) acc[i] = (f32x4){0.f, 0.f, 0.f, 0.f};
        const int rt = w >> 1, chh = w & 1;
#pragma unroll 1
        for (int c = 0; c < 4; c++) {
            __syncthreads();
#pragma unroll
            for (int it = 0; it < 2; it++) {
                int qid = tid + it * 512;
                int kk = qid >> 5, cq = qid & 31;
                float4 a = *reinterpret_cast<const float4*>(Wn + (size_t)(c * 32 + kk) * 128 + cq * 4);
                WnT[cq * 4 + 0][kk] = f2bf(a.x);
                WnT[cq * 4 + 1][kk] = f2bf(a.y);
                WnT[cq * 4 + 2][kk] = f2bf(a.z);
                WnT[cq * 4 + 3][kk] = f2bf(a.w);
            }
            __syncthreads();
            bf16x8 a = *reinterpret_cast<const bf16x8*>(&Xs[rt * 16 + (l & 15)][c * 32 + (l >> 4) * 8]);
#pragma unroll
            for (int n2 = 0; n2 < 4; n2++) {
                int n = (chh * 4 + n2) * 16 + (l & 15);
                bf16x8 b = *reinterpret_cast<const bf16x8*>(&WnT[n][(l >> 4) * 8]);
                acc[n2] = __builtin_amdgcn_mfma_f32_16x16x32_bf16(a, b, acc[n2], 0, 0, 0);
            }
        }
        const int lrow0 = rt * 16 + ((l >> 4) << 2);
#pragma unroll
        for (int n2 = 0; n2 < 4; n2++) {
            int col = (chh * 4 + n2) * 16 + (l & 15);
#pragma unroll
            for (int r = 0; r < 4; r++) {
                int row = rbase + lrow0 + r;
                if (isE) {
                    if (row < R) EWn16[(size_t)row * 128 + col] = f2bf(acc[n2][r]);
                } else {
                    int c_out = row >> 5, rem = row & 31;
                    int i = c_out * 4096 + (col >> 4) * 512
                          + ((rem >> 3) * 16 + (col & 15)) * 8 + (rem & 7);
                    WhpWnFrag[i] = f2bf(acc[n2][r]);
                }
            }
        }
    }
}

// ---------------- fused re-bin + gather + GEMM + pos path (256 threads, 16 nodes) ----------------
__global__ __launch_bounds__(256) void k_fused(const float* __restrict__ h,
                                               const float* __restrict__ pos,
                                               const float* __restrict__ nrm,
                                               const unsigned short* __restrict__ h16,
                                               const unsigned short* __restrict__ EWn16,
                                               const int* __restrict__ gcnt,
                                               const unsigned* __restrict__ gbuf,
                                               const unsigned short* __restrict__ WhpWnFrag,
                                               const unsigned short* __restrict__ LwFrag,
                                               const float* __restrict__ WpW,
                                               const float* __restrict__ Ew,
                                               const float* __restrict__ Lwp,
                                               const float* __restrict__ Ewp,
                                               float* __restrict__ out, int N, int R) {
    __shared__ unsigned eplists[16][CAP2];       // 3 KB
    __shared__ int lcnt2[16];
    __shared__ float psumS[16][4];
    __shared__ unsigned short hpsumS[16][136];   // 4.25 KB
    __shared__ unsigned short esumS[16][136];    // 4.25 KB
    __shared__ unsigned short hsh[16][136];      // 4.25 KB
    __shared__ float WpWS[3][128];
    __shared__ float nrmS[16];
    __shared__ int zrowsS[16];
    __shared__ int nzS;
    const int tid = threadIdx.x;
    const int rbase = blockIdx.x * 16;
    const int w = tid >> 6, lane = tid & 63;
    const int half = lane >> 5;
    const int g = (lane >> 4) & 1, l16 = lane & 15;

    // pre-fill eplists with dummy entries pointing at ZERO rows (h16[N], EWn16[R])
    {
        const unsigned dummy = (unsigned)N | ((unsigned)R << 16);
        unsigned* ep = &eplists[0][0];
        for (int i = tid; i < 16 * CAP2; i += 256) ep[i] = dummy;
    }
    if (tid >= 64 && tid < 192) {
        int i = tid - 64;
        WpWS[0][i] = WpW[i]; WpWS[1][i] = WpW[128 + i]; WpWS[2][i] = WpW[256 + i];
    }
    if (tid == 192) nzS = 0;
    if (tid < 16) {
        int row = rbase + tid;
        nrmS[tid] = (row < N) ? nrm[row] : 0.f;
        lcnt2[tid] = 0;
    }
    __syncthreads();

    // phase 0: re-bin bucket into per-dst LDS lists
    const int cntB = min(gcnt[blockIdx.x], BS);
    for (int i = tid; i < cntB; i += 256) {
        unsigned v = gbuf[(size_t)blockIdx.x * BS + i];
        int d = v & 15;
        int off = atomicAdd(&lcnt2[d], 1);
        if (off < CAP2) eplists[d][off] = v >> 4;   // src | type<<16
    }
    __syncthreads();

    if (tid < 16) {
        int row = rbase + tid;
        if (row < N && lcnt2[tid] == 0) {
            int o = atomicAdd(&nzS, 1);
            zrowsS[o] = tid;
        }
    }
    // psum: 48 dedicated threads, exact fp32, no atomics (overlaps others' phase 1)
    if (tid < 64) {
        int d = tid >> 2, j = tid & 3;
        if (j < 3) {
            float s = 0.f;
            int m = min(lcnt2[d], CAP2);
            int i = 0;
            for (; i + 4 <= m; i += 4) {
                unsigned s0 = eplists[d][i] & 0xffffu;
                unsigned s1 = eplists[d][i + 1] & 0xffffu;
                unsigned s2 = eplists[d][i + 2] & 0xffffu;
                unsigned s3 = eplists[d][i + 3] & 0xffffu;
                float a = pos[(size_t)s0 * 3 + j];
                float b = pos[(size_t)s1 * 3 + j];
                float c = pos[(size_t)s2 * 3 + j];
                float e = pos[(size_t)s3 * 3 + j];
                s += (a + b) + (c + e);
            }
            for (; i < m; i++) s += pos[(size_t)(eplists[d][i] & 0xffffu) * 3 + j];
            psumS[d][j] = s;
        }
    }

    const uint4* h4 = reinterpret_cast<const uint4*>(h16);
    const uint4* e4 = reinterpret_cast<const uint4*>(EWn16);

    // phase 1: 2 passes x 8 streams; g0 sums h16 rows, g1 sums EWn16 rows.
    // No masking: tail entries are dummies that read the zero rows.
#pragma unroll 1
    for (int p = 0; p < 2; p++) {
        const int base2 = p * 8 + w * 2;
        const int vl = base2 + half;
        const int mm = (max(min(lcnt2[base2], CAP2), min(lcnt2[base2 + 1], CAP2)) + 7) & ~7;
        float a[8];
#pragma unroll
        for (int r = 0; r < 8; r++) a[r] = 0.f;
        const unsigned* epr = &eplists[vl][0];
        const uint4* basep = g ? e4 : h4;
#pragma unroll 1
        for (int j = 0; j < mm; j += 8) {
            uint4 rv[8];
#pragma unroll
            for (int u = 0; u < 8; u++) {
                unsigned pk = epr[j + u];
                unsigned ridx = g ? (pk >> 16) : (pk & 0xffffu);
                rv[u] = basep[(size_t)ridx * 16u + l16];
            }
#pragma unroll
            for (int u = 0; u < 8; u++) {
                a[0] += bflo(rv[u].x); a[1] += bfhi(rv[u].x);
                a[2] += bflo(rv[u].y); a[3] += bfhi(rv[u].y);
                a[4] += bflo(rv[u].z); a[5] += bfhi(rv[u].z);
                a[6] += bflo(rv[u].w); a[7] += bfhi(rv[u].w);
            }
        }
        float nf = nrmS[vl];
        unsigned pk4[4];
#pragma unroll
        for (int q = 0; q < 4; q++) {
            pk4[q] = (unsigned)f2bf(nf * a[2 * q]) | ((unsigned)f2bf(nf * a[2 * q + 1]) << 16);
        }
        unsigned short* dst = g ? &esumS[vl][0] : &hpsumS[vl][0];
        *reinterpret_cast<uint4*>(&dst[l16 * 8]) = make_uint4(pk4[0], pk4[1], pk4[2], pk4[3]);
    }

    // stage h tile from h16 (one uint4 per thread)
    {
        int rr = tid >> 4, q = tid & 15;
        int row = rbase + rr;
        uint4 v = make_uint4(0, 0, 0, 0);
        if (row < N)
            v = reinterpret_cast<const uint4*>(h16)[(size_t)row * 16 + q];
        *reinterpret_cast<uint4*>(&hsh[rr][q * 8]) = v;
    }
    __syncthreads();

    // phase 2: acc = (nf*hsum)@WhpWn + h@Lw ; 4 waves x 2 col-tiles, M=16, 8 chunks
    f32x4 acc[2];
    acc[0] = (f32x4){0.f, 0.f, 0.f, 0.f};
    acc[1] = (f32x4){0.f, 0.f, 0.f, 0.f};
    const int arow = lane & 15;
#pragma unroll
    for (int c = 0; c < 8; c++) {
        uint4 raw;
        const bf16x8* Bp;
        if (c < 4) {
            raw = *reinterpret_cast<const uint4*>(&hpsumS[arow][c * 32 + (lane >> 4) * 8]);
            Bp = reinterpret_cast<const bf16x8*>(WhpWnFrag) + (size_t)c * 512;
        } else {
            raw = *reinterpret_cast<const uint4*>(&hsh[arow][(c & 3) * 32 + (lane >> 4) * 8]);
            Bp = reinterpret_cast<const bf16x8*>(LwFrag) + (size_t)(c & 3) * 512;
        }
        bf16x8 a = *reinterpret_cast<bf16x8*>(&raw);
#pragma unroll
        for (int n2 = 0; n2 < 2; n2++) {
            bf16x8 b = Bp[(w * 2 + n2) * 64 + lane];
            acc[n2] = __builtin_amdgcn_mfma_f32_16x16x32_bf16(a, b, acc[n2], 0, 0, 0);
        }
    }
    const int lrow0 = (lane >> 4) << 2;
#pragma unroll
    for (int n2 = 0; n2 < 2; n2++) {
        int col = (w * 2 + n2) * 16 + (lane & 15);
        float wp0 = WpWS[0][col], wp1 = WpWS[1][col], wp2 = WpWS[2][col];
#pragma unroll
        for (int r = 0; r < 4; r++) {
            int lr = lrow0 + r;
            int grow = rbase + lr;
            if (grow < N && lcnt2[lr] > 0) {
                float nfr = nrmS[lr];
                float es = bflo((unsigned)esumS[lr][col]);
                float pterm = psumS[lr][0] * wp0 + psumS[lr][1] * wp1 + psumS[lr][2] * wp2;
                float v = acc[n2][r] + es + nfr * pterm;
                out[(size_t)grow * 128 + col] = fmaxf(v, 0.f);
            }
        }
    }
    // rare deg==0 patch: out = relu(h @ Ew), exact fp32 (block-uniform, ~never runs)
    for (int zi = 0; zi < nzS; zi++) {
        int r = zrowsS[zi];
        int row = rbase + r;
        if (tid < 128) {
            float accp = 0.f;
            for (int k = 0; k < 128; k++)
                accp += h[(size_t)row * 128 + k] * Ew[k * 128 + tid];
            out[(size_t)row * 128 + tid] = fmaxf(accp, 0.f);
        }
    }
    // pos path
    if (tid < 16) {
        int row = rbase + tid;
        if (row < N) {
            float p0 = pos[(size_t)row * 3 + 0];
            float p1 = pos[(size_t)row * 3 + 1];
            float p2 = pos[(size_t)row * 3 + 2];
            const float* M = (lcnt2[tid] > 0) ? Lwp : Ewp;
            float o0 = p0 + (p0 * M[0] + p1 * M[3] + p2 * M[6]);
            float o1 = p1 + (p0 * M[1] + p1 * M[4] + p2 * M[7]);
            float o2 = p2 + (p0 * M[2] + p1 * M[5] + p2 * M[8]);
            size_t base = (size_t)N * 128 + (size_t)row * 3;
            out[base + 0] = fmaxf(o0, 0.f);
            out[base + 1] = fmaxf(o1, 0.f);
            out[base + 2] = fmaxf(o2, 0.f);
        }
    }
}

extern "C" void kernel_launch(void* const* d_in, const int* in_sizes, int n_in,
                              void* d_out, int out_size, void* d_ws, size_t ws_size,
                              hipStream_t stream) {
    const float* h   = (const float*)d_in[0];
    const float* pos = (const float*)d_in[1];
    const float* nrm = (const float*)d_in[2];
    const float* emb = (const float*)d_in[3];
    const float* Whp = (const float*)d_in[4];
    const float* bhp = (const float*)d_in[5];
    const float* Wn  = (const float*)d_in[6];
    const float* Lw  = (const float*)d_in[7];
    const float* Ew  = (const float*)d_in[8];
    const float* Lwp = (const float*)d_in[9];
    const float* Ewp = (const float*)d_in[10];
    const int* esrc  = (const int*)d_in[11];
    const int* edst  = (const int*)d_in[12];
    const int* etyp  = (const int*)d_in[13];

    const int N = in_sizes[2];
    const int E = in_sizes[11];
    const int R = in_sizes[3] / 128;

    float* out = (float*)d_out;

    char* wsb = (char*)d_ws;
    size_t off = 0;
    auto nalloc = [&](size_t bytes) { char* p = wsb + off; off += (bytes + 255) & ~(size_t)255; return p; };
    const int nbkt = (N + 15) / 16;
    const int nEB = (R + 63) / 64;
    unsigned short* h16       = (unsigned short*)nalloc((size_t)(N + 1) * 128 * 2);  // +1 zero row
    int*            gcnt      = (int*)nalloc((size_t)nbkt * 4);
    unsigned*       gbuf      = (unsigned*)nalloc((size_t)nbkt * BS * 4);
    unsigned short* EWn16     = (unsigned short*)nalloc((size_t)(nEB * 64 + 1) * 128 * 2);
    unsigned short* WhpWnFrag = (unsigned short*)nalloc(16384 * 2);
    unsigned short* LwFrag    = (unsigned short*)nalloc(16384 * 2);
    float*          WpW       = (float*)nalloc(384 * 4);

    k_zero<<<(nbkt + 511) / 512, 512, 0, stream>>>(gcnt, nbkt);

    const int nBB = (E + CH - 1) / CH;
    const int nGB = nEB + 2;
    int nPB = 256 - nBB - nGB;
    if (nPB < 16) nPB = 16;
    k_comb<<<nBB + nPB + nGB, 512, 0, stream>>>(h, Whp, bhp, Wn, Lw, emb, R,
                                                esrc, edst, etyp, E,
                                                gcnt, gbuf, h16, EWn16,
                                                WhpWnFrag, WpW, LwFrag,
                                                nBB, nPB, nEB, nbkt, N);
    k_fused<<<nbkt, 256, 0, stream>>>(h, pos, nrm, h16, EWn16, gcnt, gbuf,
                                      WhpWnFrag, LwFrag, WpW, Ew, Lwp, Ewp, out, N, R);
}